// Round 2
// baseline (212.187 us; speedup 1.0000x reference)
//
#include <hip/hip_runtime.h>
#include <math.h>

#define BS        4
#define NQ        300
#define NK        17
#define LEN_Q     5100          // NQ*NK
#define N_HEADS   8
#define N_LEVELS  4
#define N_POINTS  4
#define D_MODEL   256
#define HD        32            // D_MODEL / N_HEADS

// transposed-value level bases (floats), layout vt[l][n][s][c], c contiguous
#define LB0 0
#define LB1 16777216            // + 32*16384*32
#define LB2 20971520            // + 32*4096*32
#define LB3 22020096            // + 32*1024*32
#define VT_TOTAL 22282240       // + 32*256*32
#define PROJ_OFF VT_TOTAL       // proj: (BS*LEN_Q, 384) floats

// ---------------------------------------------------------------------------
// 32xS -> Sx32 transpose per n (classic LDS tile). block (32,8), grid (S/32, 32)
// ---------------------------------------------------------------------------
__global__ __launch_bounds__(256) void transpose_kernel(
    const float* __restrict__ in, float* __restrict__ out, int S)
{
    __shared__ float t[32][33];
    int n  = blockIdx.y;
    int s0 = blockIdx.x * 32;
    const float* pin = in + (size_t)n * 32 * S;
    #pragma unroll
    for (int c = threadIdx.y; c < 32; c += 8) {
        t[c][threadIdx.x] = pin[(size_t)c * S + s0 + threadIdx.x];
    }
    __syncthreads();
    float* pout = out + (size_t)n * S * 32;
    #pragma unroll
    for (int r = threadIdx.y; r < 32; r += 8) {
        pout[(size_t)(s0 + r) * 32 + threadIdx.x] = t[threadIdx.x][r];
    }
}

// ---------------------------------------------------------------------------
// proj GEMM: C[r][j] = sum_k Q[r][k]*W[j][k] + b[j]
// W = [W_off (256 rows) ; W_attn (128 rows)], K = 256, N = 384
// BM=64, BN=64, BK=16, 256 threads, 4x4 per thread
// ---------------------------------------------------------------------------
__global__ __launch_bounds__(256) void proj_gemm(
    const float* __restrict__ Q,
    const float* __restrict__ Woff, const float* __restrict__ boff,
    const float* __restrict__ Wattn, const float* __restrict__ battn,
    float* __restrict__ P, int M)
{
    __shared__ float As[16][64];
    __shared__ float Bs[16][64];
    int bm = blockIdx.x * 64;
    int bn = blockIdx.y * 64;
    const float* W; const float* bias; int jb;
    if (bn < 256) { W = Woff;  bias = boff;  jb = bn; }
    else          { W = Wattn; bias = battn; jb = bn - 256; }

    int tid = threadIdx.x;
    int lr = tid >> 2;            // 0..63
    int lk = (tid & 3) * 4;       // 0,4,8,12
    int ty = tid >> 4;            // 0..15
    int tx = tid & 15;            // 0..15

    float acc[4][4] = {};
    for (int k0 = 0; k0 < 256; k0 += 16) {
        float4 a4 = make_float4(0.f, 0.f, 0.f, 0.f);
        int gr = bm + lr;
        if (gr < M) a4 = *(const float4*)(Q + (size_t)gr * 256 + k0 + lk);
        As[lk + 0][lr] = a4.x; As[lk + 1][lr] = a4.y;
        As[lk + 2][lr] = a4.z; As[lk + 3][lr] = a4.w;
        float4 b4 = *(const float4*)(W + (size_t)(jb + lr) * 256 + k0 + lk);
        Bs[lk + 0][lr] = b4.x; Bs[lk + 1][lr] = b4.y;
        Bs[lk + 2][lr] = b4.z; Bs[lk + 3][lr] = b4.w;
        __syncthreads();
        #pragma unroll
        for (int k = 0; k < 16; ++k) {
            float4 av = *(const float4*)&As[k][ty * 4];
            float4 bv = *(const float4*)&Bs[k][tx * 4];
            acc[0][0] += av.x * bv.x; acc[0][1] += av.x * bv.y;
            acc[0][2] += av.x * bv.z; acc[0][3] += av.x * bv.w;
            acc[1][0] += av.y * bv.x; acc[1][1] += av.y * bv.y;
            acc[1][2] += av.y * bv.z; acc[1][3] += av.y * bv.w;
            acc[2][0] += av.z * bv.x; acc[2][1] += av.z * bv.y;
            acc[2][2] += av.z * bv.z; acc[2][3] += av.z * bv.w;
            acc[3][0] += av.w * bv.x; acc[3][1] += av.w * bv.y;
            acc[3][2] += av.w * bv.z; acc[3][3] += av.w * bv.w;
        }
        __syncthreads();
    }
    #pragma unroll
    for (int i = 0; i < 4; ++i) {
        int gr = bm + ty * 4 + i;
        if (gr >= M) continue;
        float4 o;
        o.x = acc[i][0] + bias[jb + tx * 4 + 0];
        o.y = acc[i][1] + bias[jb + tx * 4 + 1];
        o.z = acc[i][2] + bias[jb + tx * 4 + 2];
        o.w = acc[i][3] + bias[jb + tx * 4 + 3];
        *(float4*)(P + (size_t)gr * 384 + bn + tx * 4) = o;
    }
}

// ---------------------------------------------------------------------------
// sampling + softmax + weighted sum. one block (256 thr) per (b, q).
// phase 1: threads 0..127 = (h, l*4+p) compute corner idx/weights + logits.
// phase 2: threads = (h, c) gather (coalesced 128B per corner) and reduce.
// ---------------------------------------------------------------------------
__global__ __launch_bounds__(256) void ms_deform_kernel(
    const float* __restrict__ rp,     // (BS, NQ, L, NK, 2)
    const float* __restrict__ proj,   // (BS*LEN_Q, 384)
    const float* __restrict__ vt,     // transposed values, all levels
    float* __restrict__ out)          // (BS, LEN_Q, 256)
{
    int bq = blockIdx.x;
    int b  = bq / LEN_Q;
    int q  = bq - b * LEN_Q;
    int qi = q / NK;
    int ki = q - qi * NK;

    __shared__ int   s_idx[128][4];
    __shared__ float s_w[128][4];
    __shared__ float s_logit[128];
    __shared__ float s_attn[128];

    int tid = threadIdx.x;
    const float* prow = proj + (size_t)bq * 384;

    if (tid < 128) {
        int h  = tid >> 4;
        int lp = tid & 15;
        int l  = lp >> 2;
        int p  = lp & 3;
        const int dims[4] = {128, 64, 32, 16};   // square levels: h == w
        int Wl = dims[l], Hl = dims[l];
        float ww = (float)Wl, hh = (float)Hl;

        size_t rbase = ((((size_t)b * NQ + qi) * N_LEVELS + l) * NK + ki) * 2;
        float rx = rp[rbase + 0];
        float ry = rp[rbase + 1];
        int oj = ((h * N_LEVELS + l) * N_POINTS + p) * 2;
        float ox = prow[oj], oy = prow[oj + 1];
        float locx = rx + ox / ww;
        float locy = ry + oy / hh;
        // grid_sample align_corners=False: x = loc*w - 0.5
        float x = locx * ww - 0.5f;
        float y = locy * hh - 0.5f;
        float x0f = floorf(x), y0f = floorf(y);
        float wx1 = x - x0f, wy1 = y - y0f;
        float wx0 = 1.f - wx1, wy0 = 1.f - wy1;
        int x0 = (int)x0f, y0 = (int)y0f;
        #pragma unroll
        for (int corner = 0; corner < 4; ++corner) {
            int xi = x0 + (corner & 1);
            int yi = y0 + (corner >> 1);
            float wgt = ((corner & 1) ? wx1 : wx0) * ((corner >> 1) ? wy1 : wy0);
            bool valid = (xi >= 0) && (xi < Wl) && (yi >= 0) && (yi < Hl);
            s_idx[tid][corner] = valid ? (yi * Wl + xi) * HD : 0;
            s_w[tid][corner]   = valid ? wgt : 0.f;
        }
        s_logit[tid] = prow[256 + h * 16 + lp];
    }
    __syncthreads();

    if (tid < 8) {
        float mx = -1e30f;
        #pragma unroll
        for (int i = 0; i < 16; ++i) mx = fmaxf(mx, s_logit[tid * 16 + i]);
        float sum = 0.f;
        #pragma unroll
        for (int i = 0; i < 16; ++i) sum += __expf(s_logit[tid * 16 + i] - mx);
        float inv = 1.f / sum;
        #pragma unroll
        for (int i = 0; i < 16; ++i)
            s_attn[tid * 16 + i] = __expf(s_logit[tid * 16 + i] - mx) * inv;
    }
    __syncthreads();

    int h = tid >> 5;
    int c = tid & 31;
    int n = b * N_HEADS + h;
    const size_t lb[4]  = {LB0, LB1, LB2, LB3};
    const int    Ssz[4] = {16384, 4096, 1024, 256};

    float acc = 0.f;
    #pragma unroll
    for (int l = 0; l < 4; ++l) {
        const float* vbase = vt + lb[l] + (size_t)n * Ssz[l] * HD + c;
        #pragma unroll
        for (int p = 0; p < 4; ++p) {
            int e = h * 16 + l * 4 + p;
            float a = s_attn[e];
            float s = 0.f;
            #pragma unroll
            for (int k2 = 0; k2 < 4; ++k2) {
                s += s_w[e][k2] * vbase[s_idx[e][k2]];
            }
            acc += a * s;
        }
    }
    out[(size_t)bq * 256 + tid] = acc;
}

// ---------------------------------------------------------------------------
extern "C" void kernel_launch(void* const* d_in, const int* in_sizes, int n_in,
                              void* d_out, int out_size, void* d_ws, size_t ws_size,
                              hipStream_t stream)
{
    const float* query = (const float*)d_in[0];
    const float* refp  = (const float*)d_in[1];
    const float* v0    = (const float*)d_in[2];
    const float* v1    = (const float*)d_in[3];
    const float* v2    = (const float*)d_in[4];
    const float* v3    = (const float*)d_in[5];
    const float* Woff  = (const float*)d_in[6];
    const float* boff  = (const float*)d_in[7];
    const float* Wattn = (const float*)d_in[8];
    const float* battn = (const float*)d_in[9];
    float* out  = (float*)d_out;
    float* vt   = (float*)d_ws;
    float* proj = vt + PROJ_OFF;

    // 1) transpose values to (n, s, c)
    transpose_kernel<<<dim3(16384 / 32, 32), dim3(32, 8), 0, stream>>>(v0, vt + LB0, 16384);
    transpose_kernel<<<dim3(4096  / 32, 32), dim3(32, 8), 0, stream>>>(v1, vt + LB1, 4096);
    transpose_kernel<<<dim3(1024  / 32, 32), dim3(32, 8), 0, stream>>>(v2, vt + LB2, 1024);
    transpose_kernel<<<dim3(256   / 32, 32), dim3(32, 8), 0, stream>>>(v3, vt + LB3, 256);

    // 2) fused projection GEMM -> (M, 384) = [off(256) | attn_logits(128)]
    int M = BS * LEN_Q;
    proj_gemm<<<dim3((M + 63) / 64, 6), 256, 0, stream>>>(
        query, Woff, boff, Wattn, battn, proj, M);

    // 3) sampling + softmax + weighted reduction
    ms_deform_kernel<<<M, 256, 0, stream>>>(refp, proj, vt, out);
}

// Round 5
// 156.078 us; speedup vs baseline: 1.3595x; 1.3595x over previous
//
#include <hip/hip_runtime.h>
#include <math.h>

#define BS        4
#define NQ        300
#define NK        17
#define LEN_Q     5100          // NQ*NK
#define N_HEADS   8
#define N_LEVELS  4
#define N_POINTS  4
#define D_MODEL   256
#define HD        32            // D_MODEL / N_HEADS

// transposed-value level bases (floats), layout vt[l][n][s][c], c contiguous
#define LB0 0
#define LB1 16777216            // + 32*16384*32
#define LB2 20971520            // + 32*4096*32
#define LB3 22020096            // + 32*1024*32
#define VT_TOTAL 22282240       // + 32*256*32
#define PROJ_OFF VT_TOTAL       // proj: (BS*LEN_Q, 384) floats

typedef __attribute__((ext_vector_type(8))) short bf16x8;
typedef __attribute__((ext_vector_type(4))) float f32x4;

// ---------------------------------------------------------------------------
// 32xS -> Sx32 transpose per n (classic LDS tile). block (32,8), grid (S/32, 32)
// ---------------------------------------------------------------------------
__global__ __launch_bounds__(256) void transpose_kernel(
    const float* __restrict__ in, float* __restrict__ out, int S)
{
    __shared__ float t[32][33];
    int n  = blockIdx.y;
    int s0 = blockIdx.x * 32;
    const float* pin = in + (size_t)n * 32 * S;
    #pragma unroll
    for (int c = threadIdx.y; c < 32; c += 8) {
        t[c][threadIdx.x] = pin[(size_t)c * S + s0 + threadIdx.x];
    }
    __syncthreads();
    float* pout = out + (size_t)n * S * 32;
    #pragma unroll
    for (int r = threadIdx.y; r < 32; r += 8) {
        pout[(size_t)(s0 + r) * 32 + threadIdx.x] = t[threadIdx.x][r];
    }
}

// ---------------------------------------------------------------------------
// bf16 helpers (RNE)
// ---------------------------------------------------------------------------
__device__ __forceinline__ short f2bf(float x) {
    unsigned u = __float_as_uint(x);
    unsigned r = (u + 0x7fffu + ((u >> 16) & 1u)) >> 16;
    return (short)r;
}
__device__ __forceinline__ bf16x8 cvt8(const float* __restrict__ p) {
    float4 a = *(const float4*)p;
    float4 b = *(const float4*)(p + 4);
    bf16x8 r;
    r[0] = f2bf(a.x); r[1] = f2bf(a.y); r[2] = f2bf(a.z); r[3] = f2bf(a.w);
    r[4] = f2bf(b.x); r[5] = f2bf(b.y); r[6] = f2bf(b.z); r[7] = f2bf(b.w);
    return r;
}

// ---------------------------------------------------------------------------
// MFMA proj GEMM: P[r][j] = sum_k Q[r][k]*W[j][k] + b[j]
// W = [W_off (256 rows) ; W_attn (128 rows)], K = 256, N = 384, M = 20400
// block = 256 thr (4 waves), tile BM=64 x BN=128; wave = 32x64 (2x4 frags).
// A,B fragments loaded straight from global fp32, converted to bf16 in regs.
// mfma_f32_16x16x32_bf16: A lane: m=lane&15, k=(lane>>4)*8+j (row-major, 8
// contiguous k -> 2x float4); B lane: n=lane&15, same k (W row-major = B^T).
// C/D: col=lane&15, row=(lane>>4)*4+reg.
// ---------------------------------------------------------------------------
__global__ __launch_bounds__(256) void proj_gemm_mfma(
    const float* __restrict__ Q,
    const float* __restrict__ Woff, const float* __restrict__ boff,
    const float* __restrict__ Wattn, const float* __restrict__ battn,
    float* __restrict__ P, int M)
{
    int tid  = threadIdx.x;
    int wave = tid >> 6;
    int lane = tid & 63;
    int bm = blockIdx.y * 64;           // grid.y: 319 row-blocks
    int bn = blockIdx.x * 128;          // grid.x: 3 col-blocks (n fastest)
    int wm = (wave & 1) * 32;
    int wn = (wave >> 1) * 64;
    int lr = lane & 15;
    int lk = (lane >> 4) * 8;

    f32x4 acc[2][4] = {};
    for (int k0 = 0; k0 < 256; k0 += 32) {
        bf16x8 afrag[2], bfrag[4];
        #pragma unroll
        for (int i = 0; i < 2; ++i) {
            int row = bm + wm + i * 16 + lr;
            row = row < M ? row : M - 1;         // clamp; stores are guarded
            afrag[i] = cvt8(Q + (size_t)row * 256 + k0 + lk);
        }
        #pragma unroll
        for (int j = 0; j < 4; ++j) {
            int n = bn + wn + j * 16 + lr;
            const float* wp = (n < 256) ? (Woff + (size_t)n * 256)
                                        : (Wattn + (size_t)(n - 256) * 256);
            bfrag[j] = cvt8(wp + k0 + lk);
        }
        #pragma unroll
        for (int i = 0; i < 2; ++i)
            #pragma unroll
            for (int j = 0; j < 4; ++j)
                acc[i][j] = __builtin_amdgcn_mfma_f32_16x16x32_bf16(
                    afrag[i], bfrag[j], acc[i][j], 0, 0, 0);
    }

    #pragma unroll
    for (int i = 0; i < 2; ++i) {
        int mbase = bm + wm + i * 16 + (lane >> 4) * 4;
        #pragma unroll
        for (int j = 0; j < 4; ++j) {
            int n = bn + wn + j * 16 + (lane & 15);
            float bias = (n < 256) ? boff[n] : battn[n - 256];
            #pragma unroll
            for (int r = 0; r < 4; ++r) {
                int row = mbase + r;
                if (row < M) P[(size_t)row * 384 + n] = acc[i][j][r] + bias;
            }
        }
    }
}

// ---------------------------------------------------------------------------
// sampling + softmax + weighted sum. one block (256 thr) per (b, q).
// phase 1 (tid<128, tid=(h,l,p)): corner indices + logits.
// softmax (tid<8, per h), then fold attn into corner weights -> s_iw int2.
// phase 2: tid = (l, h, c4); float4 gathers (8 lanes cover a 128B row),
//          accumulate over p,corner; LDS-reduce over l; float4 store.
// ---------------------------------------------------------------------------
__global__ __launch_bounds__(256) void ms_deform_kernel(
    const float* __restrict__ rp,     // (BS, NQ, L, NK, 2)
    const float* __restrict__ proj,   // (BS*LEN_Q, 384)
    const float* __restrict__ vt,     // transposed values, all levels
    float* __restrict__ out)          // (BS, LEN_Q, 256)
{
    int bq = blockIdx.x;
    int b  = bq / LEN_Q;
    int q  = bq - b * LEN_Q;
    int qi = q / NK;
    int ki = q - qi * NK;

    __shared__ int2  s_iw[128][4];    // (idx, weight-with-attn) per corner
    __shared__ float s_logit[128];
    __shared__ float s_attn[128];
    __shared__ float s_wraw[128][4];  // bilinear corner weights (pre-attn)
    __shared__ float4 s_red[256];

    int tid = threadIdx.x;
    const float* prow = proj + (size_t)bq * 384;

    if (tid < 128) {
        int h  = tid >> 4;
        int lp = tid & 15;
        int l  = lp >> 2;
        int p  = lp & 3;
        const int dims[4] = {128, 64, 32, 16};   // square levels
        int Wl = dims[l], Hl = dims[l];
        float ww = (float)Wl, hh = (float)Hl;

        size_t rbase = ((((size_t)b * NQ + qi) * N_LEVELS + l) * NK + ki) * 2;
        float rx = rp[rbase + 0];
        float ry = rp[rbase + 1];
        int oj = ((h * N_LEVELS + l) * N_POINTS + p) * 2;
        float ox = prow[oj], oy = prow[oj + 1];
        // grid_sample align_corners=False: x = loc*w - 0.5
        float x = (rx + ox / ww) * ww - 0.5f;
        float y = (ry + oy / hh) * hh - 0.5f;
        float x0f = floorf(x), y0f = floorf(y);
        float wx1 = x - x0f, wy1 = y - y0f;
        float wx0 = 1.f - wx1, wy0 = 1.f - wy1;
        int x0 = (int)x0f, y0 = (int)y0f;
        #pragma unroll
        for (int corner = 0; corner < 4; ++corner) {
            int xi = x0 + (corner & 1);
            int yi = y0 + (corner >> 1);
            float wgt = ((corner & 1) ? wx1 : wx0) * ((corner >> 1) ? wy1 : wy0);
            bool valid = (xi >= 0) && (xi < Wl) && (yi >= 0) && (yi < Hl);
            s_iw[tid][corner].x = valid ? (yi * Wl + xi) * HD : 0;
            s_wraw[tid][corner] = valid ? wgt : 0.f;
        }
        s_logit[tid] = prow[256 + h * 16 + lp];
    }
    __syncthreads();

    if (tid < 8) {
        float mx = -1e30f;
        #pragma unroll
        for (int i = 0; i < 16; ++i) mx = fmaxf(mx, s_logit[tid * 16 + i]);
        float sum = 0.f;
        #pragma unroll
        for (int i = 0; i < 16; ++i) sum += __expf(s_logit[tid * 16 + i] - mx);
        float inv = 1.f / sum;
        #pragma unroll
        for (int i = 0; i < 16; ++i)
            s_attn[tid * 16 + i] = __expf(s_logit[tid * 16 + i] - mx) * inv;
    }
    __syncthreads();

    if (tid < 128) {
        float a = s_attn[tid];
        #pragma unroll
        for (int corner = 0; corner < 4; ++corner)
            s_iw[tid][corner].y = __float_as_int(s_wraw[tid][corner] * a);
    }
    __syncthreads();

    // phase 2: tid = l*64 + h*8 + c4
    int l  = tid >> 6;
    int h  = (tid >> 3) & 7;
    int c4 = tid & 7;
    int n  = b * N_HEADS + h;
    const size_t lb[4]  = {LB0, LB1, LB2, LB3};
    const int    Ssz[4] = {16384, 4096, 1024, 256};

    const float* vbase = vt + lb[l] + (size_t)n * Ssz[l] * HD + c4 * 4;
    int ebase = h * 16 + l * 4;

    float4 acc = make_float4(0.f, 0.f, 0.f, 0.f);
    #pragma unroll
    for (int p = 0; p < 4; ++p) {
        int e = ebase + p;
        int4 iw01 = *(const int4*)&s_iw[e][0];   // corners 0,1
        int4 iw23 = *(const int4*)&s_iw[e][2];   // corners 2,3
        {
            float w = __int_as_float(iw01.y);
            float4 v = *(const float4*)(vbase + iw01.x);
            acc.x += w * v.x; acc.y += w * v.y; acc.z += w * v.z; acc.w += w * v.w;
        }
        {
            float w = __int_as_float(iw01.w);
            float4 v = *(const float4*)(vbase + iw01.z);
            acc.x += w * v.x; acc.y += w * v.y; acc.z += w * v.z; acc.w += w * v.w;
        }
        {
            float w = __int_as_float(iw23.y);
            float4 v = *(const float4*)(vbase + iw23.x);
            acc.x += w * v.x; acc.y += w * v.y; acc.z += w * v.z; acc.w += w * v.w;
        }
        {
            float w = __int_as_float(iw23.w);
            float4 v = *(const float4*)(vbase + iw23.z);
            acc.x += w * v.x; acc.y += w * v.y; acc.z += w * v.z; acc.w += w * v.w;
        }
    }

    s_red[tid] = acc;
    __syncthreads();
    if (tid < 64) {
        float4 a0 = s_red[tid];
        float4 a1 = s_red[tid + 64];
        float4 a2 = s_red[tid + 128];
        float4 a3 = s_red[tid + 192];
        float4 o;
        o.x = a0.x + a1.x + a2.x + a3.x;
        o.y = a0.y + a1.y + a2.y + a3.y;
        o.z = a0.z + a1.z + a2.z + a3.z;
        o.w = a0.w + a1.w + a2.w + a3.w;
        // tid = h*8 + c4 -> channel offset = h*32 + c4*4 = tid*4
        *(float4*)(out + (size_t)bq * 256 + tid * 4) = o;
    }
}

// ---------------------------------------------------------------------------
extern "C" void kernel_launch(void* const* d_in, const int* in_sizes, int n_in,
                              void* d_out, int out_size, void* d_ws, size_t ws_size,
                              hipStream_t stream)
{
    const float* query = (const float*)d_in[0];
    const float* refp  = (const float*)d_in[1];
    const float* v0    = (const float*)d_in[2];
    const float* v1    = (const float*)d_in[3];
    const float* v2    = (const float*)d_in[4];
    const float* v3    = (const float*)d_in[5];
    const float* Woff  = (const float*)d_in[6];
    const float* boff  = (const float*)d_in[7];
    const float* Wattn = (const float*)d_in[8];
    const float* battn = (const float*)d_in[9];
    float* out  = (float*)d_out;
    float* vt   = (float*)d_ws;
    float* proj = vt + PROJ_OFF;

    // 1) transpose values to (n, s, c)
    transpose_kernel<<<dim3(16384 / 32, 32), dim3(32, 8), 0, stream>>>(v0, vt + LB0, 16384);
    transpose_kernel<<<dim3(4096  / 32, 32), dim3(32, 8), 0, stream>>>(v1, vt + LB1, 4096);
    transpose_kernel<<<dim3(1024  / 32, 32), dim3(32, 8), 0, stream>>>(v2, vt + LB2, 1024);
    transpose_kernel<<<dim3(256   / 32, 32), dim3(32, 8), 0, stream>>>(v3, vt + LB3, 256);

    // 2) fused projection MFMA GEMM -> (M, 384) = [off(256) | attn_logits(128)]
    int M = BS * LEN_Q;                       // 20400
    proj_gemm_mfma<<<dim3(3, (M + 63) / 64), 256, 0, stream>>>(
        query, Woff, boff, Wattn, battn, proj, M);

    // 3) sampling + softmax + weighted reduction
    ms_deform_kernel<<<M, 256, 0, stream>>>(refp, proj, vt, out);
}